// Round 2
// 117.726 us; speedup vs baseline: 1.0171x; 1.0171x over previous
//
#include <hip/hip_runtime.h>
#include <math.h>

#define IMG   512
#define NIMG  24
#define XST   72     // X stride (halfs): 36 dw == 4 mod 8, rows 16B-aligned
#define TST   104    // T' stride (row length 96)
#define RST   56     // R stride (row length 48)
#define UST   88     // U' stride (row length 80)
#define UOFF  4480   // U' offset in pool1 (R = 80*56 = 4480)
#define P1SZ  7296   // max(X 96*72=6912, R+U' 4480+2816=7296)
#define TSZ   (48 * TST)

typedef _Float16 v8h __attribute__((ext_vector_type(8)));
typedef float    v4f __attribute__((ext_vector_type(4)));

__device__ __forceinline__ v8h load8(const _Float16* p) {
    union { uint4 u; v8h h; } c;
    c.u = *(const uint4*)p;
    return c.h;
}

__device__ __forceinline__ unsigned pkrtz(float a, float b) {
    union { __fp16 __attribute__((ext_vector_type(2))) v; unsigned u; } c;
    c.v = __builtin_amdgcn_cvt_pkrtz(a, b);
    return c.u;
}

__device__ __forceinline__ void store4(_Float16* p, v4f a) {
    union { _Float16 h[4]; uint2 u; } c;
    c.h[0] = (_Float16)a[0]; c.h[1] = (_Float16)a[1];
    c.h[2] = (_Float16)a[2]; c.h[3] = (_Float16)a[3];
    *(uint2*)p = c.u;
}

__device__ __forceinline__ void store4abs(_Float16* p, v4f a) {
    union { _Float16 h[4]; uint2 u; } c;
    c.h[0] = (_Float16)fabsf(a[0]); c.h[1] = (_Float16)fabsf(a[1]);
    c.h[2] = (_Float16)fabsf(a[2]); c.h[3] = (_Float16)fabsf(a[3]);
    *(uint2*)p = c.u;
}

// float -> bf16 bits, round-to-nearest-even (input non-NaN)
__device__ __forceinline__ unsigned short f2bf(float f) {
    unsigned b = __float_as_uint(f);
    b = (b + 0x7fffu + ((b >> 16) & 1u)) >> 16;
    return (unsigned short)b;
}

__device__ __forceinline__ int refl(int g) {
    return g < 0 ? -g : (g >= IMG ? 2 * IMG - 2 - g : g);
}

// ---------------- stage 1: MFMA banded-conv pipeline ----------------
// modes: 0: h[v]  1: lpdf[v]=(-1)^v h[15-v]  2: |h[v]|  3: |h[15-v]|
__global__ __launch_bounds__(512, 6) void stego_stage1(
    const float* __restrict__ x, const float* __restrict__ hpdf,
    unsigned short* __restrict__ rho_out, float2* __restrict__ bmm)
{
    __shared__ __align__(16) _Float16 pool1[P1SZ];   // X (96x72), then R (80x56) + U' (32x88)
    __shared__ __align__(16) _Float16 sTL[TSZ];      // T_L' [col j][row i], 48 x 104
    __shared__ __align__(16) _Float16 sTH[TSZ];      // T_H'
    __shared__ __align__(16) _Float16 btab[512];     // band coef table, 4 modes x 128
    __shared__ float red[16];

    const int tid = threadIdx.x;
    const int lane = tid & 63;
    const int wid = __builtin_amdgcn_readfirstlane(tid >> 6);   // wave-uniform -> SALU
    const int n16 = lane & 15, quad = lane >> 4;

    // XCD-swizzled block decode: all 128 tiles of an image land on one XCD's L2
    const int blk = blockIdx.x;
    const int xcd = blk & 7;
    const int grp = blk >> 3;                 // 0..383
    const int img = xcd + ((grp >> 7) << 3);  // XCD c serves images {c, c+8, c+16}
    const int tl  = grp & 127;
    const int Oi = (tl >> 4) << 6;
    const int Oj = (tl & 15) << 5;
    const float* ximg = x + (size_t)img * (IMG * IMG);

    // band table: btab[mode*128 + p] = c_mode[p-16] for p in [16,32), else 0
    {
        const int mode = tid >> 7, t = tid & 127;
        float v = 0.f;
        if (t >= 16 && t < 32) {
            int tap = t - 16;
            int idx = (mode == 0 || mode == 2) ? tap : 15 - tap;
            float c = hpdf[idx];
            if (mode == 1 && (tap & 1)) c = -c;
            if (mode >= 2) c = fabsf(c);
            v = c;
        }
        btab[tid] = (_Float16)v;
    }

    // ---- load X as fp16: rows Oi-15..Oi+78 (94 rows), cols Oj-16..Oj+47 (64 cols),
    //      rows 94..95 zeroed. Interior path: 3 aligned float4 loads / thread. ----
    {
        const int cg = tid & 15, row0 = tid >> 4;    // 16 col-quads x 32 rows, 3 steps
        const int c0 = Oj - 16 + 4 * cg;
        _Float16* dst = pool1 + row0 * XST + 4 * cg;
        if (Oi >= 15 && Oi <= 433 && Oj >= 16 && Oj <= 464) {
            const float* src = ximg + (size_t)(Oi - 15 + row0) * IMG + c0;
            #pragma unroll
            for (int k = 0; k < 3; ++k) {
                const int row = row0 + (k << 5);
                uint2 pv = make_uint2(0u, 0u);
                if (row < 94) {
                    float4 xv = *(const float4*)(src + (size_t)(k << 5) * IMG);
                    pv.x = pkrtz(xv.x, xv.y);
                    pv.y = pkrtz(xv.z, xv.w);
                }
                *(uint2*)(dst + (size_t)(k << 5) * XST) = pv;
            }
        } else {
            const int gj0 = refl(c0),     gj1 = refl(c0 + 1);
            const int gj2 = refl(c0 + 2), gj3 = refl(c0 + 3);
            #pragma unroll
            for (int k = 0; k < 3; ++k) {
                const int row = row0 + (k << 5);
                uint2 pv = make_uint2(0u, 0u);
                if (row < 94) {
                    const float* rsrc = ximg + (size_t)refl(Oi - 15 + row) * IMG;
                    pv.x = pkrtz(rsrc[gj0], rsrc[gj1]);
                    pv.y = pkrtz(rsrc[gj2], rsrc[gj3]);
                }
                *(uint2*)(dst + (size_t)(k << 5) * XST) = pv;
            }
        }
    }
    __syncthreads();

    // ---- band fragments ----
    // band[4]: UNSHIFTED  B[k][n] = c[k-n]    -> used by stages B, C, D (buffers unshifted)
    // bandA[2]: SHIFTED   B[k][n] = c[k-n-1]  -> used ONLY by stage A (X tile starts Oj-16)
    v8h band[4], bandA[2];
    {
        const int boff  = 16 + quad * 8 - n16;   // unshifted
        const int boffA = 15 + quad * 8 - n16;   // shifted by one (X col origin -1)
        #pragma unroll
        for (int m = 0; m < 4; ++m)
            #pragma unroll
            for (int j = 0; j < 8; ++j)
                band[m][j] = btab[m * 128 + boff + j];
        #pragma unroll
        for (int m = 0; m < 2; ++m)
            #pragma unroll
            for (int j = 0; j < 8; ++j)
                bandA[m][j] = btab[m * 128 + boffA + j];
    }

    // ---- stage A: hconv X -> T_L', T_H' (18 tiles, shared A-frag, 2 MFMA each) ----
    // T[m][n] = sum_t X[m][n+1+t] c[t]  (X col v = global Oj-16+v) == conv start Oj-15+n
    for (int u = wid; u < 18; u += 8) {
        int mt = u % 6, nt = u / 6;
        int m0 = mt * 16, n0 = nt * 16;
        v8h a = load8(pool1 + (m0 + n16) * XST + n0 + quad * 8);
        v4f z = {0.f, 0.f, 0.f, 0.f};
        v4f cL = __builtin_amdgcn_mfma_f32_16x16x32_f16(a, bandA[1], z, 0, 0, 0);
        v4f cH = __builtin_amdgcn_mfma_f32_16x16x32_f16(a, bandA[0], z, 0, 0, 0);
        int off = (n0 + n16) * TST + m0 + quad * 4;   // T'[col][row..row+3]
        store4(sTL + off, cL);
        store4(sTH + off, cH);
    }
    __syncthreads();

    float rho[4] = {0.f, 0.f, 0.f, 0.f};
    _Float16* Rb = pool1;
    _Float16* Ub = pool1 + UOFF;

    const int fB[3] = {0, 1, 0};   // HL: a=H, LH: a=L, HH: a=H
    const int fC[3] = {2, 3, 3};   // b2 mode
    const int fD[3] = {3, 2, 3};   // a2 mode

    #pragma unroll
    for (int f = 0; f < 3; ++f) {
        const _Float16* Tsrc = (f == 0) ? sTL : sTH;

        // B: vconv T -> R = |.| (15 tiles)
        for (int u = wid; u < 15; u += 8) {
            int nt = u % 5, mt = u / 5;
            int i0 = nt * 16, c0 = mt * 16;
            v8h a = load8(Tsrc + (c0 + n16) * TST + i0 + quad * 8);
            v4f z = {0.f, 0.f, 0.f, 0.f};
            v4f acc = __builtin_amdgcn_mfma_f32_16x16x32_f16(a, band[fB[f]], z, 0, 0, 0);
            store4abs(Rb + (i0 + n16) * RST + c0 + quad * 4, acc);
        }
        __syncthreads();

        // C: hconv R -> U' (10 tiles)
        for (int u = wid; u < 10; u += 8) {
            int mt = u % 5, nt = u / 5;
            int i0 = mt * 16, j0 = nt * 16;
            v8h a = load8(Rb + (i0 + n16) * RST + j0 + quad * 8);
            v4f z = {0.f, 0.f, 0.f, 0.f};
            v4f acc = __builtin_amdgcn_mfma_f32_16x16x32_f16(a, band[fC[f]], z, 0, 0, 0);
            store4(Ub + (j0 + n16) * UST + i0 + quad * 4, acc);
        }
        __syncthreads();

        // D: vconv U -> xi; rho += 1/xi (8 tiles, 1/wave)
        {
            int i0 = (wid & 3) * 16, c0 = (wid >> 2) * 16;
            v8h a = load8(Ub + (c0 + n16) * UST + i0 + quad * 8);
            v4f z = {0.f, 0.f, 0.f, 0.f};
            v4f acc = __builtin_amdgcn_mfma_f32_16x16x32_f16(a, band[fD[f]], z, 0, 0, 0);
            #pragma unroll
            for (int r = 0; r < 4; ++r) rho[r] += __builtin_amdgcn_rcpf(acc[r]);
        }
        // no barrier: next B writes R (disjoint from U'); U' overwritten only after next barrier
    }

    // ---- finalize: clamp/NaN, bf16 round, store NATURAL layout (aligned uint2),
    //      roll is applied at stage2 read. Per-block min/max unchanged. ----
    const size_t rbase = (size_t)img * (IMG * IMG);
    const int i_nat = Oi + (wid & 3) * 16 + n16;
    const int jb = Oj + ((wid >> 2) << 4) + quad * 4;
    float lmin = 1e38f, lmax = 0.f;
    unsigned pk0, pk1;
    {
        unsigned short b[4];
        #pragma unroll
        for (int r = 0; r < 4; ++r) {
            float v = rho[r];
            v = isnan(v) ? 1e10f : fminf(v, 1e10f);
            b[r] = f2bf(v);
            float rq = __uint_as_float((unsigned)b[r] << 16);
            lmin = fminf(lmin, rq);
            lmax = fmaxf(lmax, rq);
        }
        pk0 = (unsigned)b[0] | ((unsigned)b[1] << 16);
        pk1 = (unsigned)b[2] | ((unsigned)b[3] << 16);
    }
    *(uint2*)(rho_out + rbase + ((size_t)i_nat << 9) + jb) = make_uint2(pk0, pk1);

    #pragma unroll
    for (int off = 32; off >= 1; off >>= 1) {
        lmin = fminf(lmin, __shfl_xor(lmin, off));
        lmax = fmaxf(lmax, __shfl_xor(lmax, off));
    }
    if ((tid & 63) == 0) { red[wid] = lmin; red[8 + wid] = lmax; }
    __syncthreads();
    if (tid == 0) {
        float m0 = red[0], m1 = red[8];
        #pragma unroll
        for (int k = 1; k < 8; ++k) { m0 = fminf(m0, red[k]); m1 = fmaxf(m1, red[8 + k]); }
        bmm[(img << 7) + tl] = make_float2(m0, m1);
    }
}

// ---------------- stage 2: reduce minmax + rolled read + normalize + sigmoid + multiply ----------------
__global__ __launch_bounds__(256) void stego_stage2(
    const float* __restrict__ x, const unsigned short* __restrict__ rho,
    const float2* __restrict__ bmm, float* __restrict__ out)
{
    __shared__ float sred[8];
    const int tid = threadIdx.x;
    const int lane = tid & 63;

    // same XCD swizzle as stage1: read rho/x from the L2 that produced them
    const int blk = blockIdx.x;
    const int xcd = blk & 7, grp = blk >> 3;
    const int img = xcd + ((grp >> 7) << 3);
    const int chunk = grp & 127;                 // 128 blocks per image, 4 rows each
    const int t = (img << 15) + (chunk << 8) + tid;

    float lmn = 1e38f, lmx = 0.f;
    if (tid < 128) { float2 p = bmm[(img << 7) + tid]; lmn = p.x; lmx = p.y; }
    #pragma unroll
    for (int off = 32; off >= 1; off >>= 1) {
        lmn = fminf(lmn, __shfl_xor(lmn, off));
        lmx = fmaxf(lmx, __shfl_xor(lmx, off));
    }
    if (tid < 128 && (tid & 63) == 0) { sred[tid >> 6] = lmn; sred[4 + (tid >> 6)] = lmx; }
    __syncthreads();
    const float mn = fminf(sred[0], sred[1]);
    const float mx = fmaxf(sred[4], sred[5]);
    const float inv = __builtin_amdgcn_rcpf(mx - mn + 1e-8f);

    // rolled rho: rho_rolled[i][j] = rho_nat[(i-1)&511][(j-1)&511].
    // One wave == one 512-px row, so the j-1 shift is a single intra-wave shfl.
    const int i = (t >> 6) & 511;
    const int rrow = (i - 1) & 511;
    const size_t rb_off = ((size_t)img << 18) + ((size_t)rrow << 9) + ((size_t)lane << 3);
    uint4 rb = *(const uint4*)(rho + rb_off);
    unsigned ru[4] = {rb.x, rb.y, rb.z, rb.w};
    float f7 = __uint_as_float(ru[3] & 0xffff0000u);   // nat col 8*lane+7
    float r[8];
    r[0] = __shfl(f7, (lane + 63) & 63);               // prev lane's col 7 (wraps to col 511)
    r[1] = __uint_as_float(ru[0] << 16);
    r[2] = __uint_as_float(ru[0] & 0xffff0000u);
    r[3] = __uint_as_float(ru[1] << 16);
    r[4] = __uint_as_float(ru[1] & 0xffff0000u);
    r[5] = __uint_as_float(ru[2] << 16);
    r[6] = __uint_as_float(ru[2] & 0xffff0000u);
    r[7] = __uint_as_float(ru[3] << 16);

    const size_t base = (size_t)t << 3;
    const float* xrow = x + base;
    float4 xa = *(const float4*)xrow;
    float4 xb = *(const float4*)(xrow + 4);
    float xs[8] = {xa.x, xa.y, xa.z, xa.w, xb.x, xb.y, xb.z, xb.w};
    float os[8];
    #pragma unroll
    for (int k = 0; k < 8; ++k) {
        float rn = (r[k] - mn) * inv;
        os[k] = xs[k] * __builtin_amdgcn_rcpf(1.f + __expf(rn - 1.f));  // x * sigmoid(1-rn)
    }
    float* orow = out + base;
    *(float4*)orow       = make_float4(os[0], os[1], os[2], os[3]);
    *(float4*)(orow + 4) = make_float4(os[4], os[5], os[6], os[7]);
}

extern "C" void kernel_launch(void* const* d_in, const int* in_sizes, int n_in,
                              void* d_out, int out_size, void* d_ws, size_t ws_size,
                              hipStream_t stream) {
    const float* x    = (const float*)d_in[0];
    const float* hpdf = (const float*)d_in[1];
    float* out = (float*)d_out;

    unsigned short* rho = (unsigned short*)d_ws;                         // 24*512*512 bf16
    float2* bmm = (float2*)((char*)d_ws + (size_t)NIMG * IMG * IMG * 2); // 24*128 float2

    hipLaunchKernelGGL(stego_stage1, dim3(NIMG * 128), dim3(512), 0, stream,
                       x, hpdf, rho, bmm);
    hipLaunchKernelGGL(stego_stage2, dim3(NIMG * 128), dim3(256), 0, stream,
                       x, rho, bmm, out);
}

// Round 3
// 108.568 us; speedup vs baseline: 1.1029x; 1.0844x over previous
//
#include <hip/hip_runtime.h>
#include <math.h>

#define IMG   512
#define NIMG  24
#define XST   72     // X stride (halfs): 36 dw == 4 mod 8, rows 16B-aligned
#define TST   104    // T' stride (row length 96)
#define RST   56     // R stride (row length 48)
#define UST   88     // U' stride (row length 80)

// ---- LDS pool layout (units: halfs) ----
// Phase A:  reads X [9984,16896), writes sTL/sTH [0,9984)
// Phase B:  reads sT [0,9984),    writes R0..R2 [9984,23424)
// Phase C:  reads R,              writes U0..U2 [0,8448)  (over dead sT)
// Phase D:  reads U.
// ftab (frag windows) lives in R2's tail; consumed into regs before A.
#define SA_TL  0        // 48*104 = 4992
#define SA_TH  4992     // 4992
#define SA_X   9984     // 96*72 = 6912 (dead after A; overlapped by R)
#define SA_R   9984     // 3 x 80*56 = 13440 -> [9984, 23424)
#define RSZ    4480
#define SA_U   0        // 3 x 32*88 -> [0, 8448)
#define USZ    2816
#define SA_FT  22112    // 4 modes x 41 starts x 8 halfs = 1312 -> [22112, 23424)
#define POOLSZ 23424

typedef _Float16 v8h __attribute__((ext_vector_type(8)));
typedef float    v4f __attribute__((ext_vector_type(4)));

__device__ __forceinline__ v8h load8(const _Float16* p) {
    union { uint4 u; v8h h; } c;
    c.u = *(const uint4*)p;
    return c.h;
}

__device__ __forceinline__ unsigned pkrtz(float a, float b) {
    union { __fp16 __attribute__((ext_vector_type(2))) v; unsigned u; } c;
    c.v = __builtin_amdgcn_cvt_pkrtz(a, b);
    return c.u;
}

__device__ __forceinline__ void store4(_Float16* p, v4f a) {
    union { _Float16 h[4]; uint2 u; } c;
    c.h[0] = (_Float16)a[0]; c.h[1] = (_Float16)a[1];
    c.h[2] = (_Float16)a[2]; c.h[3] = (_Float16)a[3];
    *(uint2*)p = c.u;
}

__device__ __forceinline__ void store4abs(_Float16* p, v4f a) {
    union { _Float16 h[4]; uint2 u; } c;
    c.h[0] = (_Float16)fabsf(a[0]); c.h[1] = (_Float16)fabsf(a[1]);
    c.h[2] = (_Float16)fabsf(a[2]); c.h[3] = (_Float16)fabsf(a[3]);
    *(uint2*)p = c.u;
}

// float -> bf16 bits, round-to-nearest-even (input non-NaN)
__device__ __forceinline__ unsigned short f2bf(float f) {
    unsigned b = __float_as_uint(f);
    b = (b + 0x7fffu + ((b >> 16) & 1u)) >> 16;
    return (unsigned short)b;
}

__device__ __forceinline__ int refl(int g) {
    return g < 0 ? -g : (g >= IMG ? 2 * IMG - 2 - g : g);
}

// ---------------- stage 1: MFMA banded-conv pipeline ----------------
// modes: 0: h[v]  1: lpdf[v]=(-1)^v h[15-v]  2: |h[v]|  3: |h[15-v]|
__global__ __launch_bounds__(512, 6) void stego_stage1(
    const float* __restrict__ x, const float* __restrict__ hpdf,
    unsigned short* __restrict__ rho_out, float2* __restrict__ bmm)
{
    __shared__ __align__(16) _Float16 pool[POOLSZ];
    __shared__ float red[16];

    const int tid = threadIdx.x;
    const int lane = tid & 63;
    const int wid = __builtin_amdgcn_readfirstlane(tid >> 6);   // wave-uniform -> SALU
    const int n16 = lane & 15, quad = lane >> 4;

    // XCD-swizzled block decode: all 128 tiles of an image land on one XCD's L2
    const int blk = blockIdx.x;
    const int xcd = blk & 7;
    const int grp = blk >> 3;                 // 0..383
    const int img = xcd + ((grp >> 7) << 3);  // XCD c serves images {c, c+8, c+16}
    const int tl  = grp & 127;
    const int Oi = (tl >> 4) << 6;
    const int Oj = (tl & 15) << 5;
    const float* ximg = x + (size_t)img * (IMG * IMG);

    // ---- fragment-window table: ftab[(mode*41 + s)*8 + j] = c_mode[s + j - 16]
    // (zero outside tap range). One aligned b128 read per fragment afterwards.
    for (int e = tid; e < 1312; e += 512) {
        const int mode = e >> 3 == 0 ? 0 : (e / 328);      // e / (41*8)
        const int rem  = e - mode * 328;
        const int tap  = (rem >> 3) + (rem & 7) - 16;      // s + j - 16
        float v = 0.f;
        if (tap >= 0 && tap <= 15) {
            int idx = (mode == 0 || mode == 2) ? tap : 15 - tap;
            float c = hpdf[idx];
            if (mode == 1 && (tap & 1)) c = -c;
            if (mode >= 2) c = fabsf(c);
            v = c;
        }
        pool[SA_FT + e] = (_Float16)v;
    }

    // ---- load X as fp16: rows Oi-15..Oi+78 (94 rows), cols Oj-16..Oj+47 (64 cols),
    //      rows 94..95 zeroed. Interior path: 3 aligned float4 loads / thread. ----
    {
        const int cg = tid & 15, row0 = tid >> 4;    // 16 col-quads x 32 rows, 3 steps
        const int c0 = Oj - 16 + 4 * cg;
        _Float16* dst = pool + SA_X + row0 * XST + 4 * cg;
        if (Oi >= 15 && Oi <= 433 && Oj >= 16 && Oj <= 464) {
            const float* src = ximg + (size_t)(Oi - 15 + row0) * IMG + c0;
            #pragma unroll
            for (int k = 0; k < 3; ++k) {
                const int row = row0 + (k << 5);
                uint2 pv = make_uint2(0u, 0u);
                if (row < 94) {
                    float4 xv = *(const float4*)(src + (size_t)(k << 5) * IMG);
                    pv.x = pkrtz(xv.x, xv.y);
                    pv.y = pkrtz(xv.z, xv.w);
                }
                *(uint2*)(dst + (size_t)(k << 5) * XST) = pv;
            }
        } else {
            const int gj0 = refl(c0),     gj1 = refl(c0 + 1);
            const int gj2 = refl(c0 + 2), gj3 = refl(c0 + 3);
            #pragma unroll
            for (int k = 0; k < 3; ++k) {
                const int row = row0 + (k << 5);
                uint2 pv = make_uint2(0u, 0u);
                if (row < 94) {
                    const float* rsrc = ximg + (size_t)refl(Oi - 15 + row) * IMG;
                    pv.x = pkrtz(rsrc[gj0], rsrc[gj1]);
                    pv.y = pkrtz(rsrc[gj2], rsrc[gj3]);
                }
                *(uint2*)(dst + (size_t)(k << 5) * XST) = pv;
            }
        }
    }
    __syncthreads();

    // ---- band fragments: one aligned ds_read_b128 per fragment.
    // band[4]: UNSHIFTED  B[k][n] = c[k-n]    (stages B, C, D)
    // bandA[2]: SHIFTED   B[k][n] = c[k-n-1]  (stage A only; X starts at Oj-16)
    v8h band[4], bandA[2];
    {
        const int sA = 16 + quad * 8 - n16;   // window start + 16, in [1,40]
        #pragma unroll
        for (int m = 0; m < 4; ++m)
            band[m] = load8(pool + SA_FT + (m * 41 + sA) * 8);
        #pragma unroll
        for (int m = 0; m < 2; ++m)
            bandA[m] = load8(pool + SA_FT + (m * 41 + sA - 1) * 8);
    }

    // ---- phase A: hconv X -> T_L', T_H' (18 tiles, shared A-frag, 2 MFMA each) ----
    for (int u = wid; u < 18; u += 8) {
        int mt = u % 6, nt = u / 6;
        int m0 = mt * 16, n0 = nt * 16;
        v8h a = load8(pool + SA_X + (m0 + n16) * XST + n0 + quad * 8);
        v4f z = {0.f, 0.f, 0.f, 0.f};
        v4f cL = __builtin_amdgcn_mfma_f32_16x16x32_f16(a, bandA[1], z, 0, 0, 0);
        v4f cH = __builtin_amdgcn_mfma_f32_16x16x32_f16(a, bandA[0], z, 0, 0, 0);
        int off = (n0 + n16) * TST + m0 + quad * 4;   // T'[col][row..row+3]
        store4(pool + SA_TL + off, cL);
        store4(pool + SA_TH + off, cH);
    }
    __syncthreads();

    float rho[4] = {0.f, 0.f, 0.f, 0.f};
    const int fB[3] = {0, 1, 0};   // HL: a=H, LH: a=L, HH: a=H
    const int fC[3] = {2, 3, 3};   // b2 mode
    const int fD[3] = {3, 2, 3};   // a2 mode

    // ---- phase B (fused over filters): vconv T -> R_f = |.| (45 tiles) ----
    #pragma unroll
    for (int f = 0; f < 3; ++f) {
        const _Float16* Tsrc = pool + (f == 0 ? SA_TL : SA_TH);
        _Float16* Rf = pool + SA_R + f * RSZ;
        for (int u = wid; u < 15; u += 8) {
            int nt = u % 5, mt = u / 5;
            int i0 = nt * 16, c0 = mt * 16;
            v8h a = load8(Tsrc + (c0 + n16) * TST + i0 + quad * 8);
            v4f z = {0.f, 0.f, 0.f, 0.f};
            v4f acc = __builtin_amdgcn_mfma_f32_16x16x32_f16(a, band[fB[f]], z, 0, 0, 0);
            store4abs(Rf + (i0 + n16) * RST + c0 + quad * 4, acc);
        }
    }
    __syncthreads();

    // ---- phase C (fused): hconv R_f -> U'_f (30 tiles) ----
    #pragma unroll
    for (int f = 0; f < 3; ++f) {
        const _Float16* Rf = pool + SA_R + f * RSZ;
        _Float16* Uf = pool + SA_U + f * USZ;
        for (int u = wid; u < 10; u += 8) {
            int mt = u % 5, nt = u / 5;
            int i0 = mt * 16, j0 = nt * 16;
            v8h a = load8(Rf + (i0 + n16) * RST + j0 + quad * 8);
            v4f z = {0.f, 0.f, 0.f, 0.f};
            v4f acc = __builtin_amdgcn_mfma_f32_16x16x32_f16(a, band[fC[f]], z, 0, 0, 0);
            store4(Uf + (j0 + n16) * UST + i0 + quad * 4, acc);
        }
    }
    __syncthreads();

    // ---- phase D (fused): vconv U_f -> xi; rho += 1/xi (24 tiles, 3/wave) ----
    {
        const int i0 = (wid & 3) * 16, c0 = (wid >> 2) * 16;
        #pragma unroll
        for (int f = 0; f < 3; ++f) {
            const _Float16* Uf = pool + SA_U + f * USZ;
            v8h a = load8(Uf + (c0 + n16) * UST + i0 + quad * 8);
            v4f z = {0.f, 0.f, 0.f, 0.f};
            v4f acc = __builtin_amdgcn_mfma_f32_16x16x32_f16(a, band[fD[f]], z, 0, 0, 0);
            #pragma unroll
            for (int r = 0; r < 4; ++r) rho[r] += __builtin_amdgcn_rcpf(acc[r]);
        }
    }

    // ---- finalize: clamp/NaN, bf16 round, store NATURAL layout (aligned uint2),
    //      roll is applied at stage2 read. Per-block min/max unchanged. ----
    const size_t rbase = (size_t)img * (IMG * IMG);
    const int i_nat = Oi + (wid & 3) * 16 + n16;
    const int jb = Oj + ((wid >> 2) << 4) + quad * 4;
    float lmin = 1e38f, lmax = 0.f;
    unsigned pk0, pk1;
    {
        unsigned short b[4];
        #pragma unroll
        for (int r = 0; r < 4; ++r) {
            float v = rho[r];
            v = isnan(v) ? 1e10f : fminf(v, 1e10f);
            b[r] = f2bf(v);
            float rq = __uint_as_float((unsigned)b[r] << 16);
            lmin = fminf(lmin, rq);
            lmax = fmaxf(lmax, rq);
        }
        pk0 = (unsigned)b[0] | ((unsigned)b[1] << 16);
        pk1 = (unsigned)b[2] | ((unsigned)b[3] << 16);
    }
    *(uint2*)(rho_out + rbase + ((size_t)i_nat << 9) + jb) = make_uint2(pk0, pk1);

    #pragma unroll
    for (int off = 32; off >= 1; off >>= 1) {
        lmin = fminf(lmin, __shfl_xor(lmin, off));
        lmax = fmaxf(lmax, __shfl_xor(lmax, off));
    }
    if ((tid & 63) == 0) { red[wid] = lmin; red[8 + wid] = lmax; }
    __syncthreads();
    if (tid == 0) {
        float m0 = red[0], m1 = red[8];
        #pragma unroll
        for (int k = 1; k < 8; ++k) { m0 = fminf(m0, red[k]); m1 = fmaxf(m1, red[8 + k]); }
        bmm[(img << 7) + tl] = make_float2(m0, m1);
    }
}

// ---------------- stage 2: reduce minmax + rolled read + normalize + sigmoid + multiply ----------------
__global__ __launch_bounds__(256) void stego_stage2(
    const float* __restrict__ x, const unsigned short* __restrict__ rho,
    const float2* __restrict__ bmm, float* __restrict__ out)
{
    __shared__ float sred[8];
    const int tid = threadIdx.x;
    const int lane = tid & 63;

    // same XCD swizzle as stage1: read rho/x from the L2 that produced them
    const int blk = blockIdx.x;
    const int xcd = blk & 7, grp = blk >> 3;
    const int img = xcd + ((grp >> 7) << 3);
    const int chunk = grp & 127;                 // 128 blocks per image, 4 rows each
    const int t = (img << 15) + (chunk << 8) + tid;

    float lmn = 1e38f, lmx = 0.f;
    if (tid < 128) { float2 p = bmm[(img << 7) + tid]; lmn = p.x; lmx = p.y; }
    #pragma unroll
    for (int off = 32; off >= 1; off >>= 1) {
        lmn = fminf(lmn, __shfl_xor(lmn, off));
        lmx = fmaxf(lmx, __shfl_xor(lmx, off));
    }
    if (tid < 128 && (tid & 63) == 0) { sred[tid >> 6] = lmn; sred[4 + (tid >> 6)] = lmx; }
    __syncthreads();
    const float mn = fminf(sred[0], sred[1]);
    const float mx = fmaxf(sred[4], sred[5]);
    const float inv = __builtin_amdgcn_rcpf(mx - mn + 1e-8f);

    // rolled rho: rho_rolled[i][j] = rho_nat[(i-1)&511][(j-1)&511].
    // One wave == one 512-px row, so the j-1 shift is a single intra-wave shfl.
    const int i = (t >> 6) & 511;
    const int rrow = (i - 1) & 511;
    const size_t rb_off = ((size_t)img << 18) + ((size_t)rrow << 9) + ((size_t)lane << 3);
    uint4 rb = *(const uint4*)(rho + rb_off);
    unsigned ru[4] = {rb.x, rb.y, rb.z, rb.w};
    float f7 = __uint_as_float(ru[3] & 0xffff0000u);   // nat col 8*lane+7
    float r[8];
    r[0] = __shfl(f7, (lane + 63) & 63);               // prev lane's col 7 (wraps to col 511)
    r[1] = __uint_as_float(ru[0] << 16);
    r[2] = __uint_as_float(ru[0] & 0xffff0000u);
    r[3] = __uint_as_float(ru[1] << 16);
    r[4] = __uint_as_float(ru[1] & 0xffff0000u);
    r[5] = __uint_as_float(ru[2] << 16);
    r[6] = __uint_as_float(ru[2] & 0xffff0000u);
    r[7] = __uint_as_float(ru[3] << 16);

    const size_t base = (size_t)t << 3;
    const float* xrow = x + base;
    float4 xa = *(const float4*)xrow;
    float4 xb = *(const float4*)(xrow + 4);
    float xs[8] = {xa.x, xa.y, xa.z, xa.w, xb.x, xb.y, xb.z, xb.w};
    float os[8];
    #pragma unroll
    for (int k = 0; k < 8; ++k) {
        float rn = (r[k] - mn) * inv;
        os[k] = xs[k] * __builtin_amdgcn_rcpf(1.f + __expf(rn - 1.f));  // x * sigmoid(1-rn)
    }
    float* orow = out + base;
    *(float4*)orow       = make_float4(os[0], os[1], os[2], os[3]);
    *(float4*)(orow + 4) = make_float4(os[4], os[5], os[6], os[7]);
}

extern "C" void kernel_launch(void* const* d_in, const int* in_sizes, int n_in,
                              void* d_out, int out_size, void* d_ws, size_t ws_size,
                              hipStream_t stream) {
    const float* x    = (const float*)d_in[0];
    const float* hpdf = (const float*)d_in[1];
    float* out = (float*)d_out;

    unsigned short* rho = (unsigned short*)d_ws;                         // 24*512*512 bf16
    float2* bmm = (float2*)((char*)d_ws + (size_t)NIMG * IMG * IMG * 2); // 24*128 float2

    hipLaunchKernelGGL(stego_stage1, dim3(NIMG * 128), dim3(512), 0, stream,
                       x, hpdf, rho, bmm);
    hipLaunchKernelGGL(stego_stage2, dim3(NIMG * 128), dim3(256), 0, stream,
                       x, rho, bmm, out);
}